// Round 10
// baseline (185.726 us; speedup 1.0000x reference)
//
#include <hip/hip_runtime.h>

#define DIM 128
#define BN_EPS_F 1e-5f
#define NSLICE 16   // stat slices: spreads atomic contention; preamble reduces them
#define MAXN 10240  // LDS histogram capacity (n = 10000)
#define CHUNKS 128  // edge chunks == blocks in chunkhist/scatter

typedef unsigned int u32;
typedef unsigned short u16;

__device__ __forceinline__ float bflo(u32 w) {
    union { u32 u; float f; } c; c.u = w << 16; return c.f;
}
__device__ __forceinline__ float bfhi(u32 w) {
    union { u32 u; float f; } c; c.u = w & 0xffff0000u; return c.f;
}
// pack two floats to bf16x2 with round-to-nearest-even
__device__ __forceinline__ u32 packbf(float x, float y) {
    union { float f; u32 u; } ax, ay; ax.f = x; ay.f = y;
    u32 xr = (ax.u + 0x7fffu + ((ax.u >> 16) & 1u)) >> 16;
    u32 yr = (ay.u + 0x7fffu + ((ay.u >> 16) & 1u)) >> 16;
    return xr | (yr << 16);
}

__device__ __forceinline__ void addrow(float* acc, const uint4 v) {
    acc[0] += bflo(v.x); acc[1] += bfhi(v.x);
    acc[2] += bflo(v.y); acc[3] += bfhi(v.y);
    acc[4] += bflo(v.z); acc[5] += bfhi(v.z);
    acc[6] += bflo(v.w); acc[7] += bfhi(v.w);
}

// ---------------- CSR build (atomic-free counting sort) ----------------

// A: per-chunk private LDS histogram -> hist[chunk][bin]
__global__ __launch_bounds__(256) void chunkhist_kernel(const int* __restrict__ dst,
                                                        int* __restrict__ hist,
                                                        int n, int E, int chunk) {
    __shared__ int bins[MAXN];
    int tid = threadIdx.x;
    for (int i = tid; i < n; i += 256) bins[i] = 0;
    __syncthreads();
    int e0 = blockIdx.x * chunk;
    int e1 = min(e0 + chunk, E);
    for (int e = e0 + tid; e < e1; e += 256) atomicAdd(&bins[dst[e]], 1);
    __syncthreads();
    int* out = hist + (size_t)blockIdx.x * n;
    for (int i = tid; i < n; i += 256) out[i] = bins[i];
}

// B1: per-bin exclusive prefix over chunks; counts[bin] = total degree
__global__ __launch_bounds__(256) void chunkscan_kernel(const int* __restrict__ hist,
                                                        int* __restrict__ chunkpref,
                                                        int* __restrict__ counts, int n) {
    int bin = blockIdx.x * 256 + threadIdx.x;
    if (bin >= n) return;
    const int* hp = hist + bin;
    int* cp = chunkpref + bin;
    int run = 0;
#pragma unroll 32
    for (int b = 0; b < CHUNKS; b++) {
        int v = hp[(size_t)b * n];
        cp[(size_t)b * n] = run;
        run += v;
    }
    counts[bin] = run;
}

// B2: exclusive scan of 16-PADDED counts -> prowptr (scan only)
__global__ __launch_bounds__(1024) void scan_kernel(const int* __restrict__ counts,
                                                    int* __restrict__ prowptr, int n) {
    __shared__ int sums[1024];
    const int CH = 16;
    int t = threadIdx.x;
    int base = t * CH;
    int local[CH];
    int s = 0;
#pragma unroll
    for (int i = 0; i < CH; i++) {
        int idx = base + i;
        local[i] = s;
        if (idx < n) s += (counts[idx] + 15) & ~15;
    }
    sums[t] = s;
    __syncthreads();
    for (int off = 1; off < 1024; off <<= 1) {
        int v = (t >= off) ? sums[t - off] : 0;
        __syncthreads();
        sums[t] += v;
        __syncthreads();
    }
    int prev = (t > 0) ? sums[t - 1] : 0;
#pragma unroll
    for (int i = 0; i < CH; i++) {
        int idx = base + i;
        if (idx < n) prowptr[idx] = prev + local[i];
    }
    if (t == 1023) prowptr[n] = sums[1023];
}

// B3: misc fused kernel — cvt x->bf16 (+zero dummy rows), pad-fill, zero gstats
__global__ __launch_bounds__(256) void misc_kernel(const float* __restrict__ x,
                                                   u16* __restrict__ xb,
                                                   u16* __restrict__ r0,
                                                   u16* __restrict__ r1,
                                                   const int* __restrict__ prowptr,
                                                   const int* __restrict__ counts,
                                                   int* __restrict__ srcsorted,
                                                   float* __restrict__ gstats,
                                                   int total4, int n,
                                                   int nb_cvt, int nb_pad, int gtotal) {
    int bid = blockIdx.x;
    int tid = threadIdx.x;
    if (bid < nb_cvt) {
        int i = bid * 256 + tid;
        if (i < total4) {
            float4 v = ((const float4*)x)[i];
            uint2 w;
            w.x = packbf(v.x, v.y);
            w.y = packbf(v.z, v.w);
            *(uint2*)(xb + (size_t)i * 4) = w;
        } else {
            int j = i - total4;
            if (j < 96) {
                u16* t = (j < 32) ? xb : ((j < 64) ? r0 : r1);
                uint2 z; z.x = 0; z.y = 0;
                *(uint2*)(t + (size_t)n * DIM + (j & 31) * 4) = z;
            }
        }
    } else if (bid < nb_cvt + nb_pad) {
        int i = (bid - nb_cvt) * 256 + tid;
        if (i < n) {
            int pstart = prowptr[i];
            int c = counts[i];
            int p = (c + 15) & ~15;
            for (int k = c; k < p; k++) srcsorted[pstart + k] = n;  // dummy -> zero row
        }
    } else {
        int i = (bid - nb_cvt - nb_pad) * 256 + tid;
        if (i < gtotal) gstats[i] = 0.f;
    }
}

// C: scatter via LDS-ranked positions (no global atomics)
__global__ __launch_bounds__(256) void scatter_kernel(const int* __restrict__ src,
                                                      const int* __restrict__ dst,
                                                      const int* __restrict__ prowptr,
                                                      const int* __restrict__ chunkpref,
                                                      int* __restrict__ srcsorted,
                                                      int n, int E, int chunk) {
    __shared__ int cur[MAXN];
    int tid = threadIdx.x;
    const int* cp = chunkpref + (size_t)blockIdx.x * n;
    for (int i = tid; i < n; i += 256) cur[i] = prowptr[i] + cp[i];
    __syncthreads();
    int e0 = blockIdx.x * chunk;
    int e1 = min(e0 + chunk, E);
    for (int e = e0 + tid; e < e1; e += 256) {
        int d = dst[e];
        int pos = atomicAdd(&cur[d], 1);
        srcsorted[pos] = src[e];
    }
}

// ---------------- fused affine(prev-BN) + GIN aggregate + stats ----------------
// Grid-strided: each block owns ~2 node-groups (4 nodes/wave-group). Preamble
// ab-reduce once per block; stats accumulate in REGISTERS across the block's
// nodes, single LDS reduce + atomic flush at the end. Edge loop: 16-lane
// group reads a full 256B bf16 row per uint4 load; srcs indices for the NEXT
// 32-edge tile are prefetched while current rows are in flight (pipelined).
template <int USE_AB>
__global__ __launch_bounds__(256, 4) void gather_kernel(
    const u16* __restrict__ hin, u16* __restrict__ hout,
    const int* __restrict__ prowptr, const int* __restrict__ counts,
    const int* __restrict__ srcs,
    const float* __restrict__ stats_in, float* __restrict__ stats_out,
    const float* __restrict__ gamma, const float* __restrict__ beta,
    int n, int ngroups, float inv_n) {
    __shared__ float ab_s[2 * DIM];
    __shared__ float part[2][DIM];
    __shared__ float ls[4][DIM];
    __shared__ float lq[4][DIM];
    int tid = threadIdx.x;
    int wid = tid >> 6;
    int lane = tid & 63;
    int grp = lane >> 4;   // 0..3: which edge-slot
    int sub = lane & 15;   // 16 lanes x uint4 = 256B = one bf16 row

    if (USE_AB) {
        int c = tid & 127;
        int which = tid >> 7;  // 0 = sums, 1 = squares
        const float* basep = stats_in + which * NSLICE * DIM + c;
        float acc = 0.f;
#pragma unroll
        for (int k = 0; k < NSLICE; k++) acc += basep[k * DIM];
        part[which][c] = acc;
        __syncthreads();
        if (tid < DIM) {
            float mu = part[0][tid] * inv_n;
            float var = part[1][tid] * inv_n - mu * mu;
            float av = gamma[tid] * rsqrtf(var + BN_EPS_F);
            ab_s[tid] = av;
            ab_s[DIM + tid] = beta[tid] - mu * av;
        }
        __syncthreads();
    }

    float sacc[8], qacc[8];
#pragma unroll
    for (int k = 0; k < 8; k++) { sacc[k] = 0.f; qacc[k] = 0.f; }

    for (int g = blockIdx.x; g < ngroups; g += gridDim.x) {
        int node = g * 4 + wid;
        if (node >= n) continue;
        int start = prowptr[node];
        int pend = prowptr[node + 1];
        int deg = counts[node];
        const u16* hsub = hin + sub * 8;
        float acc[8];
#pragma unroll
        for (int k = 0; k < 8; k++) acc[k] = 0.f;

        int eb = start;
        if (eb + 32 <= pend) {
            // preload first tile-pair's indices
            int e0 = eb + grp * 4;
            int s0 = srcs[e0 + 0], s1 = srcs[e0 + 1];
            int s2 = srcs[e0 + 2], s3 = srcs[e0 + 3];
            int s4 = srcs[e0 + 16], s5 = srcs[e0 + 17];
            int s6 = srcs[e0 + 18], s7 = srcs[e0 + 19];
            while (true) {
                uint4 v0 = *(const uint4*)(hsub + (size_t)s0 * DIM);
                uint4 v1 = *(const uint4*)(hsub + (size_t)s1 * DIM);
                uint4 v2 = *(const uint4*)(hsub + (size_t)s2 * DIM);
                uint4 v3 = *(const uint4*)(hsub + (size_t)s3 * DIM);
                uint4 v4 = *(const uint4*)(hsub + (size_t)s4 * DIM);
                uint4 v5 = *(const uint4*)(hsub + (size_t)s5 * DIM);
                uint4 v6 = *(const uint4*)(hsub + (size_t)s6 * DIM);
                uint4 v7 = *(const uint4*)(hsub + (size_t)s7 * DIM);
                int nb = eb + 32;
                if (nb + 32 <= pend) {
                    // prefetch next pair's indices while rows are in flight
                    int e1 = nb + grp * 4;
                    s0 = srcs[e1 + 0]; s1 = srcs[e1 + 1];
                    s2 = srcs[e1 + 2]; s3 = srcs[e1 + 3];
                    s4 = srcs[e1 + 16]; s5 = srcs[e1 + 17];
                    s6 = srcs[e1 + 18]; s7 = srcs[e1 + 19];
                }
                addrow(acc, v0); addrow(acc, v1);
                addrow(acc, v2); addrow(acc, v3);
                addrow(acc, v4); addrow(acc, v5);
                addrow(acc, v6); addrow(acc, v7);
                eb = nb;
                if (eb + 32 > pend) break;
            }
        }
        if (eb < pend) {  // one 16-edge tile remains
            int e0 = eb + grp * 4;
            int s0 = srcs[e0 + 0], s1 = srcs[e0 + 1];
            int s2 = srcs[e0 + 2], s3 = srcs[e0 + 3];
            uint4 v0 = *(const uint4*)(hsub + (size_t)s0 * DIM);
            uint4 v1 = *(const uint4*)(hsub + (size_t)s1 * DIM);
            uint4 v2 = *(const uint4*)(hsub + (size_t)s2 * DIM);
            uint4 v3 = *(const uint4*)(hsub + (size_t)s3 * DIM);
            addrow(acc, v0); addrow(acc, v1);
            addrow(acc, v2); addrow(acc, v3);
        }
        // reduce the 4 groups: all lanes end with the full per-node sum
#pragma unroll
        for (int k = 0; k < 8; k++) {
            acc[k] += __shfl_xor(acc[k], 16);
            acc[k] += __shfl_xor(acc[k], 32);
        }

        uint4 sv = *(const uint4*)(hin + (size_t)node * DIM + sub * 8);
        float self[8] = {bflo(sv.x), bfhi(sv.x), bflo(sv.y), bfhi(sv.y),
                         bflo(sv.z), bfhi(sv.z), bflo(sv.w), bfhi(sv.w)};
        float degp1 = 1.0f + (float)deg;

        float o[8];
        if (USE_AB) {
            float4 a0 = *(const float4*)(ab_s + sub * 8);
            float4 a1 = *(const float4*)(ab_s + sub * 8 + 4);
            float4 b0 = *(const float4*)(ab_s + DIM + sub * 8);
            float4 b1 = *(const float4*)(ab_s + DIM + sub * 8 + 4);
            o[0] = a0.x * (self[0] + acc[0]) + degp1 * b0.x;
            o[1] = a0.y * (self[1] + acc[1]) + degp1 * b0.y;
            o[2] = a0.z * (self[2] + acc[2]) + degp1 * b0.z;
            o[3] = a0.w * (self[3] + acc[3]) + degp1 * b0.w;
            o[4] = a1.x * (self[4] + acc[4]) + degp1 * b1.x;
            o[5] = a1.y * (self[5] + acc[5]) + degp1 * b1.y;
            o[6] = a1.z * (self[6] + acc[6]) + degp1 * b1.z;
            o[7] = a1.w * (self[7] + acc[7]) + degp1 * b1.w;
        } else {
#pragma unroll
            for (int k = 0; k < 8; k++) o[k] = self[k] + acc[k];
        }
        u32 w0 = packbf(o[0], o[1]);
        u32 w1 = packbf(o[2], o[3]);
        u32 w2 = packbf(o[4], o[5]);
        u32 w3 = packbf(o[6], o[7]);
        if (grp == 0) {
            uint4 wv; wv.x = w0; wv.y = w1; wv.z = w2; wv.w = w3;
            *(uint4*)(hout + (size_t)node * DIM + sub * 8) = wv;
        }
        float rr[8] = {bflo(w0), bfhi(w0), bflo(w1), bfhi(w1),
                       bflo(w2), bfhi(w2), bflo(w3), bfhi(w3)};
#pragma unroll
        for (int k = 0; k < 8; k++) {
            sacc[k] += rr[k];
            qacc[k] += rr[k] * rr[k];
        }
    }

    // single stats flush per block (grp 0's registers hold valid sums)
    __syncthreads();
    if (grp == 0) {
#pragma unroll
        for (int k = 0; k < 8; k++) {
            ls[wid][sub * 8 + k] = sacc[k];
            lq[wid][sub * 8 + k] = qacc[k];
        }
    }
    __syncthreads();
    int slice = (blockIdx.x & (NSLICE - 1)) * DIM;
    int c = tid & 127;
    int which = tid >> 7;
    float s = which ? ((lq[0][c] + lq[1][c]) + (lq[2][c] + lq[3][c]))
                    : ((ls[0][c] + ls[1][c]) + (ls[2][c] + ls[3][c]));
    atomicAdd(&stats_out[which * NSLICE * DIM + slice + c], s);
}

// ---------------- final affine apply (layer 3) ----------------
__global__ __launch_bounds__(256) void apply_kernel(const u16* __restrict__ hb,
                                                    const float* __restrict__ stats_in,
                                                    const float* __restrict__ gamma,
                                                    const float* __restrict__ beta,
                                                    float* __restrict__ out, int total4,
                                                    float inv_n) {
    __shared__ float ab_s[2 * DIM];
    __shared__ float part[2][DIM];
    int tid = threadIdx.x;
    {
        int c = tid & 127;
        int which = tid >> 7;
        const float* basep = stats_in + which * NSLICE * DIM + c;
        float acc = 0.f;
#pragma unroll
        for (int k = 0; k < NSLICE; k++) acc += basep[k * DIM];
        part[which][c] = acc;
        __syncthreads();
        if (tid < DIM) {
            float mu = part[0][tid] * inv_n;
            float var = part[1][tid] * inv_n - mu * mu;
            float av = gamma[tid] * rsqrtf(var + BN_EPS_F);
            ab_s[tid] = av;
            ab_s[DIM + tid] = beta[tid] - mu * av;
        }
        __syncthreads();
    }
    for (int i = blockIdx.x * blockDim.x + tid; i < total4; i += gridDim.x * blockDim.x) {
        int quad = i & 31;
        uint2 w = *(const uint2*)(hb + (size_t)i * 4);
        const float4 a = *(const float4*)(ab_s + quad * 4);
        const float4 b = *(const float4*)(ab_s + DIM + quad * 4);
        float4 r;
        r.x = a.x * bflo(w.x) + b.x;
        r.y = a.y * bfhi(w.x) + b.y;
        r.z = a.z * bflo(w.y) + b.z;
        r.w = a.w * bfhi(w.y) + b.w;
        ((float4*)out)[i] = r;
    }
}

extern "C" void kernel_launch(void* const* d_in, const int* in_sizes, int n_in,
                              void* d_out, int out_size, void* d_ws, size_t ws_size,
                              hipStream_t stream) {
    const float* x = (const float*)d_in[0];
    const float* gamma = (const float*)d_in[1];
    const float* beta = (const float*)d_in[2];
    const int* src = (const int*)d_in[3];
    const int* dst = (const int*)d_in[4];
    float* out = (float*)d_out;

    const int n = in_sizes[0] / DIM;   // 10000
    const int E = in_sizes[3];         // 640000

    char* ws = (char*)d_ws;
    auto alloc = [&](size_t bytes) -> char* {
        char* p = ws;
        ws += (bytes + 255) / 256 * 256;
        return p;
    };
    const int STATS_PER_LAYER = 2 * NSLICE * DIM;                 // sums + squares
    int* prowptr = (int*)alloc((size_t)(n + 1) * 4);
    int* counts = (int*)alloc((size_t)n * 4);
    float* gstats = (float*)alloc((size_t)4 * STATS_PER_LAYER * 4);
    int* hist = (int*)alloc((size_t)CHUNKS * n * 4);
    int* chunkpref = (int*)alloc((size_t)CHUNKS * n * 4);
    int* srcsorted = (int*)alloc((size_t)(E + 16 * n) * 4);       // padded
    u16* hbx = (u16*)alloc((size_t)(n + 1) * DIM * 2);
    u16* hb0 = (u16*)alloc((size_t)(n + 1) * DIM * 2);
    u16* hb1 = (u16*)alloc((size_t)(n + 1) * DIM * 2);

    const int chunk = (E + CHUNKS - 1) / CHUNKS;
    const int total4 = n * DIM / 4;
    const int gtotal = 4 * STATS_PER_LAYER;
    const int NB_CVT = (total4 + 96 + 255) / 256;
    const int NB_PAD = (n + 255) / 256;
    const int NB_GZ = (gtotal + 255) / 256;

    chunkhist_kernel<<<CHUNKS, 256, 0, stream>>>(dst, hist, n, E, chunk);
    chunkscan_kernel<<<(n + 255) / 256, 256, 0, stream>>>(hist, chunkpref, counts, n);
    scan_kernel<<<1, 1024, 0, stream>>>(counts, prowptr, n);
    misc_kernel<<<NB_CVT + NB_PAD + NB_GZ, 256, 0, stream>>>(x, hbx, hb0, hb1, prowptr,
                                                             counts, srcsorted, gstats,
                                                             total4, n, NB_CVT, NB_PAD,
                                                             gtotal);
    scatter_kernel<<<CHUNKS, 256, 0, stream>>>(src, dst, prowptr, chunkpref, srcsorted,
                                               n, E, chunk);

    const int ngroups = (n + 3) / 4;          // 4 nodes (1/wave) per group
    const int GB = (ngroups + 1) / 2;         // ~2 groups per block
    const float inv_n = 1.0f / n;
    float* st0 = gstats + 0 * STATS_PER_LAYER;
    float* st1 = gstats + 1 * STATS_PER_LAYER;
    float* st2 = gstats + 2 * STATS_PER_LAYER;
    float* st3 = gstats + 3 * STATS_PER_LAYER;

    gather_kernel<0><<<GB, 256, 0, stream>>>(hbx, hb0, prowptr, counts, srcsorted,
                                             nullptr, st0, nullptr, nullptr, n, ngroups,
                                             inv_n);
    gather_kernel<1><<<GB, 256, 0, stream>>>(hb0, hb1, prowptr, counts, srcsorted,
                                             st0, st1, gamma + 0 * DIM, beta + 0 * DIM,
                                             n, ngroups, inv_n);
    gather_kernel<1><<<GB, 256, 0, stream>>>(hb1, hb0, prowptr, counts, srcsorted,
                                             st1, st2, gamma + 1 * DIM, beta + 1 * DIM,
                                             n, ngroups, inv_n);
    gather_kernel<1><<<GB, 256, 0, stream>>>(hb0, hb1, prowptr, counts, srcsorted,
                                             st2, st3, gamma + 2 * DIM, beta + 2 * DIM,
                                             n, ngroups, inv_n);
    apply_kernel<<<256, 256, 0, stream>>>(hb1, st3, gamma + 3 * DIM, beta + 3 * DIM, out,
                                          total4, inv_n);
}